// Round 3
// baseline (537.298 us; speedup 1.0000x reference)
//
#include <hip/hip_runtime.h>
#include <math.h>

#define SLOPE 0.01f
#define NLAYER 15
#define FINE_CELLS 512            // [-2, 2), h = 1/128
#define COARSE_CELLS 128          // [-32, 32), h = 1/2; extrapolate outside
#define CELLS 640                 // per layer; cell = float4 (s_m, s_c, t_m, t_c) slope/intercept
#define FINE_NODES 513
#define NODES_PER_NET 642
#define INV_LN2 1.4426950408889634f
#define LN2F 0.6931471805599453f
#define TPB 512
#define PAIRS 4

__device__ __forceinline__ float fast_exp2(float x) {
#if __has_builtin(__builtin_amdgcn_exp2f)
    return __builtin_amdgcn_exp2f(x);
#else
    return __expf(x * LN2F);
#endif
}

// ---------------- exact scalar->32->16->1 MLP (precompute only) ----------------
__device__ __forceinline__ float mlp_exact(
    float x1,
    const float* __restrict__ W1, const float* __restrict__ b1,
    const float* __restrict__ W2, const float* __restrict__ b2,
    const float* __restrict__ W3, float b3)
{
    float h2[16];
#pragma unroll
    for (int n = 0; n < 16; ++n) h2[n] = b2[n];
#pragma unroll 2
    for (int j = 0; j < 32; ++j) {
        float h = fmaf(W1[j], x1, b1[j]);
        h = fmaxf(h, SLOPE * h);
#pragma unroll
        for (int n = 0; n < 16; ++n) h2[n] = fmaf(h, W2[j * 16 + n], h2[n]);
    }
    float o = b3;
#pragma unroll
    for (int n = 0; n < 16; ++n) {
        float h = fmaxf(h2[n], SLOPE * h2[n]);
        o = fmaf(h, W3[n], o);
    }
    return o;
}

// ---------------- build: one block per net (30 blocks) ----
// Cell c stores slope/intercept so eval is a single fma in x:
//   which==0 (s-net): (.x,.y) = (m, c) with ls2(x) = m*x + c   [log2 units]
//   which==1 (t-net): (.z,.w) = (m, c) with g(x)   = m*x + c
__global__ __launch_bounds__(640) void build_tables(
    const float* __restrict__ scale_w, const float* __restrict__ scale_b,
    const float* __restrict__ sW1, const float* __restrict__ sb1,
    const float* __restrict__ sW2, const float* __restrict__ sb2,
    const float* __restrict__ sW3, const float* __restrict__ sb3,
    const float* __restrict__ tW1, const float* __restrict__ tb1,
    const float* __restrict__ tW2, const float* __restrict__ tb2,
    const float* __restrict__ tW3, const float* __restrict__ tb3,
    float* __restrict__ ws)
{
    const int m = blockIdx.x;            // 0..29
    const int l = m >> 1;
    const int which = m & 1;             // 0 = s-net, 1 = t-net
    const float* W1 = (which ? tW1 : sW1) + l * 32;
    const float* b1 = (which ? tb1 : sb1) + l * 32;
    const float* W2 = (which ? tW2 : sW2) + l * 512;
    const float* b2 = (which ? tb2 : sb2) + l * 16;
    const float* W3 = (which ? tW3 : sW3) + l * 16;
    const float  b3 = which ? tb3[l] : sb3[l];

    __shared__ float nodes[NODES_PER_NET];

    for (int i = threadIdx.x; i < NODES_PER_NET; i += blockDim.x) {
        const float x = (i < FINE_NODES) ? (-2.0f + (float)i * (1.0f / 128.0f))
                                         : (-32.0f + (float)(i - FINE_NODES) * 0.5f);
        float o = mlp_exact(x, W1, b1, W2, b2, W3, b3);
        nodes[i] = which ? o : fmaf(tanhf(o), scale_w[l], scale_b[l]) * INV_LN2;
    }
    __syncthreads();

    for (int c = threadIdx.x; c < CELLS; c += blockDim.x) {
        int base; float x_lo, invh;
        if (c < FINE_CELLS) { base = c;     x_lo = -2.0f  + (float)c * (1.0f / 128.0f); invh = 128.0f; }
        else                { base = c + 1; x_lo = -32.0f + (float)(c - FINE_CELLS) * 0.5f; invh = 2.0f; }
        float lo = nodes[base], hi = nodes[base + 1];
        float slope = (hi - lo) * invh;
        float icpt  = fmaf(-slope, x_lo, lo);
        *(float2*)(ws + ((size_t)(l * CELLS + c) * 4) + which * 2) = make_float2(slope, icpt);
    }
}

// ---------------- cell index (shared by both chains) ----------------
__device__ __forceinline__ int cell_index(float x) {
    float uf = fmaf(x, 128.0f, 256.0f);            // fine cell index
    float uc = fmaf(x, 2.0f, 576.0f);              // coarse cell index in [512,640)
    bool fine = (fabsf(x) < 2.0f);
    float fu = fine ? floorf(uf)
                    : fminf(fmaxf(floorf(uc), 512.0f), 639.0f);  // clamp -> linear extrapolation
    return (int)fu;
}

// ---------------- one coupling step for a single chain pair ----------------
__device__ __forceinline__ void couple(const float4* __restrict__ T,
                                       float& z1, float& z2, float& ld)
{
    float4 c = T[cell_index(z2)];
    float ls = fmaf(c.x, z2, c.y);        // log2 scale
    float g  = fmaf(c.z, z2, c.w);
    float z2n = fmaf(fast_exp2(ls), z1, g);
    z1 = z2; z2 = z2n; ld += ls;
}

// ---------------- main flow: per-layer LDS table (10 KB, double-buffered) ------
// All 15 layers fully unrolled; 4 pairs (8 chains) of state live in registers the
// whole time; each block does 15 barriers total. LDS = 20 KB -> occupancy is
// VGPR-bound: __launch_bounds__(512,8) caps at 64 VGPR = 4 blocks/CU = 32 waves.
__global__ __launch_bounds__(TPB, 8) void flow_lut(
    const float4* __restrict__ x,      // pairs of float2 samples
    const float4* __restrict__ ws,     // [NLAYER][CELLS] slope/intercept cells
    float4* __restrict__ out_z,
    float2* __restrict__ out_ld,
    int npair)
{
    __shared__ __align__(16) float4 buf[2][CELLS];   // 20480 B
    const int nthreads = gridDim.x * blockDim.x;
    const int tid0 = blockIdx.x * blockDim.x + threadIdx.x;

    // stage layer 0 while the x loads are in flight
    for (int i = threadIdx.x; i < CELLS; i += TPB) buf[0][i] = ws[i];

    float az1[PAIRS], az2[PAIRS], ald[PAIRS];
    float bz1[PAIRS], bz2[PAIRS], bld[PAIRS];
#pragma unroll
    for (int k = 0; k < PAIRS; ++k) {
        int p = tid0 + k * nthreads;
        float4 xi = (p < npair) ? x[p] : make_float4(0.f, 0.f, 0.f, 0.f);
        az1[k] = xi.y; az2[k] = xi.x; ald[k] = 0.f;
        bz1[k] = xi.w; bz2[k] = xi.z; bld[k] = 0.f;
    }
    __syncthreads();

#pragma unroll
    for (int l = 0; l < NLAYER; ++l) {
        // prefetch next layer's table into the other buffer (off critical path)
        if (l + 1 < NLAYER) {
            const float4* src = ws + (size_t)(l + 1) * CELLS;
            for (int i = threadIdx.x; i < CELLS; i += TPB)
                buf[(l + 1) & 1][i] = src[i];
        }
        const float4* T = buf[l & 1];
#pragma unroll
        for (int k = 0; k < PAIRS; ++k) {
            couple(T, az1[k], az2[k], ald[k]);
            couple(T, bz1[k], bz2[k], bld[k]);
        }
        __syncthreads();   // next layer's buffer staged AND this layer's reads done
    }

#pragma unroll
    for (int k = 0; k < PAIRS; ++k) {
        int p = tid0 + k * nthreads;
        if (p < npair) {
            out_z[p]  = make_float4(az1[k], az2[k], bz1[k], bz2[k]);
            out_ld[p] = make_float2(ald[k] * LN2F, bld[k] * LN2F);
        }
    }
}

extern "C" void kernel_launch(void* const* d_in, const int* in_sizes, int n_in,
                              void* d_out, int out_size, void* d_ws, size_t ws_size,
                              hipStream_t stream) {
    const int n = in_sizes[0] / 2;
    const int npair = n / 2;             // N = 4194304 is even

    const float4* x       = (const float4*)d_in[0];
    const float*  scale_w = (const float*)d_in[1];
    const float*  scale_b = (const float*)d_in[2];
    const float*  sW1     = (const float*)d_in[3];
    const float*  sb1     = (const float*)d_in[4];
    const float*  sW2     = (const float*)d_in[5];
    const float*  sb2     = (const float*)d_in[6];
    const float*  sW3     = (const float*)d_in[7];
    const float*  sb3     = (const float*)d_in[8];
    const float*  tW1     = (const float*)d_in[9];
    const float*  tb1     = (const float*)d_in[10];
    const float*  tW2     = (const float*)d_in[11];
    const float*  tb2     = (const float*)d_in[12];
    const float*  tW3     = (const float*)d_in[13];
    const float*  tb3     = (const float*)d_in[14];

    float4* out_z  = (float4*)d_out;
    float2* out_ld = (float2*)((float*)d_out + (size_t)2 * n);

    build_tables<<<30, 640, 0, stream>>>(scale_w, scale_b,
        sW1, sb1, sW2, sb2, sW3, sb3,
        tW1, tb1, tW2, tb2, tW3, tb3, (float*)d_ws);

    const int nblocks = (npair + TPB * PAIRS - 1) / (TPB * PAIRS);   // 1024 for N=4.19M
    flow_lut<<<nblocks, TPB, 0, stream>>>(x, (const float4*)d_ws, out_z, out_ld, npair);
}

// Round 4
// 180.212 us; speedup vs baseline: 2.9815x; 2.9815x over previous
//
#include <hip/hip_runtime.h>
#include <math.h>

#define SLOPE 0.01f
#define NLAYER 15
#define FINE_CELLS 512            // [-2, 2), h = 1/128
#define COARSE_CELLS 128          // [-32, 32), h = 1/2; extrapolate outside
#define CELLS 640                 // per layer; cell = float4 (s_m, s_c, t_m, t_c) slope/intercept
#define FINE_NODES 513
#define NODES_PER_NET 642
#define INV_LN2 1.4426950408889634f
#define LN2F 0.6931471805599453f
#define TPB 512
#define PAIRS 4

__device__ __forceinline__ float fast_exp2(float x) {
#if __has_builtin(__builtin_amdgcn_exp2f)
    return __builtin_amdgcn_exp2f(x);
#else
    return __expf(x * LN2F);
#endif
}

// ---------------- exact scalar->32->16->1 MLP (precompute only) ----------------
__device__ __forceinline__ float mlp_exact(
    float x1,
    const float* __restrict__ W1, const float* __restrict__ b1,
    const float* __restrict__ W2, const float* __restrict__ b2,
    const float* __restrict__ W3, float b3)
{
    float h2[16];
#pragma unroll
    for (int n = 0; n < 16; ++n) h2[n] = b2[n];
#pragma unroll 2
    for (int j = 0; j < 32; ++j) {
        float h = fmaf(W1[j], x1, b1[j]);
        h = fmaxf(h, SLOPE * h);
#pragma unroll
        for (int n = 0; n < 16; ++n) h2[n] = fmaf(h, W2[j * 16 + n], h2[n]);
    }
    float o = b3;
#pragma unroll
    for (int n = 0; n < 16; ++n) {
        float h = fmaxf(h2[n], SLOPE * h2[n]);
        o = fmaf(h, W3[n], o);
    }
    return o;
}

// ---------------- build: one block per net (30 blocks) ----
// Cell c stores slope/intercept so eval is a single fma in x:
//   which==0 (s-net): (.x,.y) = (m, c) with ls2(x) = m*x + c   [log2 units]
//   which==1 (t-net): (.z,.w) = (m, c) with g(x)   = m*x + c
__global__ __launch_bounds__(640) void build_tables(
    const float* __restrict__ scale_w, const float* __restrict__ scale_b,
    const float* __restrict__ sW1, const float* __restrict__ sb1,
    const float* __restrict__ sW2, const float* __restrict__ sb2,
    const float* __restrict__ sW3, const float* __restrict__ sb3,
    const float* __restrict__ tW1, const float* __restrict__ tb1,
    const float* __restrict__ tW2, const float* __restrict__ tb2,
    const float* __restrict__ tW3, const float* __restrict__ tb3,
    float* __restrict__ ws)
{
    const int m = blockIdx.x;            // 0..29
    const int l = m >> 1;
    const int which = m & 1;             // 0 = s-net, 1 = t-net
    const float* W1 = (which ? tW1 : sW1) + l * 32;
    const float* b1 = (which ? tb1 : sb1) + l * 32;
    const float* W2 = (which ? tW2 : sW2) + l * 512;
    const float* b2 = (which ? tb2 : sb2) + l * 16;
    const float* W3 = (which ? tW3 : sW3) + l * 16;
    const float  b3 = which ? tb3[l] : sb3[l];

    __shared__ float nodes[NODES_PER_NET];

    for (int i = threadIdx.x; i < NODES_PER_NET; i += blockDim.x) {
        const float x = (i < FINE_NODES) ? (-2.0f + (float)i * (1.0f / 128.0f))
                                         : (-32.0f + (float)(i - FINE_NODES) * 0.5f);
        float o = mlp_exact(x, W1, b1, W2, b2, W3, b3);
        nodes[i] = which ? o : fmaf(tanhf(o), scale_w[l], scale_b[l]) * INV_LN2;
    }
    __syncthreads();

    for (int c = threadIdx.x; c < CELLS; c += blockDim.x) {
        int base; float x_lo, invh;
        if (c < FINE_CELLS) { base = c;     x_lo = -2.0f  + (float)c * (1.0f / 128.0f); invh = 128.0f; }
        else                { base = c + 1; x_lo = -32.0f + (float)(c - FINE_CELLS) * 0.5f; invh = 2.0f; }
        float lo = nodes[base], hi = nodes[base + 1];
        float slope = (hi - lo) * invh;
        float icpt  = fmaf(-slope, x_lo, lo);
        *(float2*)(ws + ((size_t)(l * CELLS + c) * 4) + which * 2) = make_float2(slope, icpt);
    }
}

// ---------------- cell index (shared by both chains) ----------------
__device__ __forceinline__ int cell_index(float x) {
    float uf = fmaf(x, 128.0f, 256.0f);            // fine cell index
    float uc = fmaf(x, 2.0f, 576.0f);              // coarse cell index in [512,640)
    bool fine = (fabsf(x) < 2.0f);
    float fu = fine ? floorf(uf)
                    : fminf(fmaxf(floorf(uc), 512.0f), 639.0f);  // clamp -> linear extrapolation
    return (int)fu;
}

// ---------------- one coupling step for a single chain pair ----------------
__device__ __forceinline__ void couple(const float4* __restrict__ T,
                                       float& z1, float& z2, float& ld)
{
    float4 c = T[cell_index(z2)];
    float ls = fmaf(c.x, z2, c.y);        // log2 scale
    float g  = fmaf(c.z, z2, c.w);
    float z2n = fmaf(fast_exp2(ls), z1, g);
    z1 = z2; z2 = z2n; ld += ls;
}

// ---------------- main flow: per-layer LDS table (10 KB, double-buffered) ------
// All 15 layers fully unrolled; 4 pairs (8 chains) of state live in registers the
// whole time; each block does 15 barriers total. LDS = 20 KB.
// NOTE: no min-waves clamp in __launch_bounds__ — R3 showed (512,8) forces a
// 32-VGPR allocation and ~1.3 GB of scratch spill traffic (437 us). The design
// relies on per-wave gather ILP (8 independent chains), not occupancy.
__global__ __launch_bounds__(TPB) void flow_lut(
    const float4* __restrict__ x,      // pairs of float2 samples
    const float4* __restrict__ ws,     // [NLAYER][CELLS] slope/intercept cells
    float4* __restrict__ out_z,
    float2* __restrict__ out_ld,
    int npair)
{
    __shared__ __align__(16) float4 buf[2][CELLS];   // 20480 B
    const int nthreads = gridDim.x * blockDim.x;
    const int tid0 = blockIdx.x * blockDim.x + threadIdx.x;

    // stage layer 0 while the x loads are in flight
    for (int i = threadIdx.x; i < CELLS; i += TPB) buf[0][i] = ws[i];

    float az1[PAIRS], az2[PAIRS], ald[PAIRS];
    float bz1[PAIRS], bz2[PAIRS], bld[PAIRS];
#pragma unroll
    for (int k = 0; k < PAIRS; ++k) {
        int p = tid0 + k * nthreads;
        float4 xi = (p < npair) ? x[p] : make_float4(0.f, 0.f, 0.f, 0.f);
        az1[k] = xi.y; az2[k] = xi.x; ald[k] = 0.f;
        bz1[k] = xi.w; bz2[k] = xi.z; bld[k] = 0.f;
    }
    __syncthreads();

#pragma unroll
    for (int l = 0; l < NLAYER; ++l) {
        // prefetch next layer's table into the other buffer (off critical path)
        if (l + 1 < NLAYER) {
            const float4* src = ws + (size_t)(l + 1) * CELLS;
            for (int i = threadIdx.x; i < CELLS; i += TPB)
                buf[(l + 1) & 1][i] = src[i];
        }
        const float4* T = buf[l & 1];
#pragma unroll
        for (int k = 0; k < PAIRS; ++k) {
            couple(T, az1[k], az2[k], ald[k]);
            couple(T, bz1[k], bz2[k], bld[k]);
        }
        __syncthreads();   // next layer's buffer staged AND this layer's reads done
    }

#pragma unroll
    for (int k = 0; k < PAIRS; ++k) {
        int p = tid0 + k * nthreads;
        if (p < npair) {
            out_z[p]  = make_float4(az1[k], az2[k], bz1[k], bz2[k]);
            out_ld[p] = make_float2(ald[k] * LN2F, bld[k] * LN2F);
        }
    }
}

extern "C" void kernel_launch(void* const* d_in, const int* in_sizes, int n_in,
                              void* d_out, int out_size, void* d_ws, size_t ws_size,
                              hipStream_t stream) {
    const int n = in_sizes[0] / 2;
    const int npair = n / 2;             // N = 4194304 is even

    const float4* x       = (const float4*)d_in[0];
    const float*  scale_w = (const float*)d_in[1];
    const float*  scale_b = (const float*)d_in[2];
    const float*  sW1     = (const float*)d_in[3];
    const float*  sb1     = (const float*)d_in[4];
    const float*  sW2     = (const float*)d_in[5];
    const float*  sb2     = (const float*)d_in[6];
    const float*  sW3     = (const float*)d_in[7];
    const float*  sb3     = (const float*)d_in[8];
    const float*  tW1     = (const float*)d_in[9];
    const float*  tb1     = (const float*)d_in[10];
    const float*  tW2     = (const float*)d_in[11];
    const float*  tb2     = (const float*)d_in[12];
    const float*  tW3     = (const float*)d_in[13];
    const float*  tb3     = (const float*)d_in[14];

    float4* out_z  = (float4*)d_out;
    float2* out_ld = (float2*)((float*)d_out + (size_t)2 * n);

    build_tables<<<30, 640, 0, stream>>>(scale_w, scale_b,
        sW1, sb1, sW2, sb2, sW3, sb3,
        tW1, tb1, tW2, tb2, tW3, tb3, (float*)d_ws);

    const int nblocks = (npair + TPB * PAIRS - 1) / (TPB * PAIRS);   // 1024 for N=4.19M
    flow_lut<<<nblocks, TPB, 0, stream>>>(x, (const float4*)d_ws, out_z, out_ld, npair);
}

// Round 5
// 148.711 us; speedup vs baseline: 3.6130x; 1.2118x over previous
//
#include <hip/hip_runtime.h>
#include <math.h>

#define SLOPE 0.01f
#define NLAYER 15
#define FINE_CELLS 512            // [-2, 2), h = 1/128
#define COARSE_CELLS 128          // [-32, 32), h = 1/2; extrapolate outside via clamped end cells
#define CELLS 640                 // per layer; cell = float4 (s_m, s_c, t_m, t_c) slope/intercept
#define FINE_NODES 513
#define NODES_PER_NET 642
#define TABLE_FLOAT4 (NLAYER * CELLS)        // 9600 float4 = 153600 B
#define INV_LN2 1.4426950408889634f
#define LN2F 0.6931471805599453f

__device__ __forceinline__ float fast_exp2(float x) {
#if __has_builtin(__builtin_amdgcn_exp2f)
    return __builtin_amdgcn_exp2f(x);
#else
    return __expf(x * LN2F);
#endif
}

// ---------------- exact scalar->32->16->1 MLP (precompute only) ----------------
__device__ __forceinline__ float mlp_exact(
    float x1,
    const float* __restrict__ W1, const float* __restrict__ b1,
    const float* __restrict__ W2, const float* __restrict__ b2,
    const float* __restrict__ W3, float b3)
{
    float h2[16];
#pragma unroll
    for (int n = 0; n < 16; ++n) h2[n] = b2[n];
#pragma unroll 2
    for (int j = 0; j < 32; ++j) {
        float h = fmaf(W1[j], x1, b1[j]);
        h = fmaxf(h, SLOPE * h);
#pragma unroll
        for (int n = 0; n < 16; ++n) h2[n] = fmaf(h, W2[j * 16 + n], h2[n]);
    }
    float o = b3;
#pragma unroll
    for (int n = 0; n < 16; ++n) {
        float h = fmaxf(h2[n], SLOPE * h2[n]);
        o = fmaf(h, W3[n], o);
    }
    return o;
}

// ---------------- build: one block per net (30 blocks) ----
// Cell c stores slope/intercept so eval is a single fma in x:
//   which==0 (s-net): (.x,.y) = (m, c) with ls2(x) = m*x + c   [log2 units]
//   which==1 (t-net): (.z,.w) = (m, c) with g(x)   = m*x + c
// (verified correct in R4: same absmax 0.125 as the lerp table)
__global__ __launch_bounds__(640) void build_tables(
    const float* __restrict__ scale_w, const float* __restrict__ scale_b,
    const float* __restrict__ sW1, const float* __restrict__ sb1,
    const float* __restrict__ sW2, const float* __restrict__ sb2,
    const float* __restrict__ sW3, const float* __restrict__ sb3,
    const float* __restrict__ tW1, const float* __restrict__ tb1,
    const float* __restrict__ tW2, const float* __restrict__ tb2,
    const float* __restrict__ tW3, const float* __restrict__ tb3,
    float* __restrict__ ws)
{
    const int m = blockIdx.x;            // 0..29
    const int l = m >> 1;
    const int which = m & 1;             // 0 = s-net, 1 = t-net
    const float* W1 = (which ? tW1 : sW1) + l * 32;
    const float* b1 = (which ? tb1 : sb1) + l * 32;
    const float* W2 = (which ? tW2 : sW2) + l * 512;
    const float* b2 = (which ? tb2 : sb2) + l * 16;
    const float* W3 = (which ? tW3 : sW3) + l * 16;
    const float  b3 = which ? tb3[l] : sb3[l];

    __shared__ float nodes[NODES_PER_NET];

    for (int i = threadIdx.x; i < NODES_PER_NET; i += blockDim.x) {
        const float x = (i < FINE_NODES) ? (-2.0f + (float)i * (1.0f / 128.0f))
                                         : (-32.0f + (float)(i - FINE_NODES) * 0.5f);
        float o = mlp_exact(x, W1, b1, W2, b2, W3, b3);
        nodes[i] = which ? o : fmaf(tanhf(o), scale_w[l], scale_b[l]) * INV_LN2;
    }
    __syncthreads();

    for (int c = threadIdx.x; c < CELLS; c += blockDim.x) {
        int base; float x_lo, invh;
        if (c < FINE_CELLS) { base = c;     x_lo = -2.0f  + (float)c * (1.0f / 128.0f); invh = 128.0f; }
        else                { base = c + 1; x_lo = -32.0f + (float)(c - FINE_CELLS) * 0.5f; invh = 2.0f; }
        float lo = nodes[base], hi = nodes[base + 1];
        float slope = (hi - lo) * invh;
        float icpt  = fmaf(-slope, x_lo, lo);
        *(float2*)(ws + ((size_t)(l * CELLS + c) * 4) + which * 2) = make_float2(slope, icpt);
    }
}

// ---------------- cell index ----------------
// Fine: uf = 128x+256 in [0,512) -> trunc == floor (non-negative).
// Coarse: clamp int index to [512,639]; clamped end cells extrapolate linearly.
__device__ __forceinline__ int cell_index(float x) {
    float uf = fmaf(x, 128.0f, 256.0f);
    float uc = fmaf(x, 2.0f, 576.0f);
    bool fine = (fabsf(x) < 2.0f);
    int ic = min(max((int)uc, 512), 639);
    return fine ? (int)uf : ic;
}

// ---------------- one coupling step for a single chain ----------------
__device__ __forceinline__ void couple(const float4* __restrict__ T,
                                       float& z1, float& z2, float& ld)
{
    float4 c = T[cell_index(z2)];
    float ls = fmaf(c.x, z2, c.y);        // log2 scale
    float g  = fmaf(c.z, z2, c.w);
    float z2n = fmaf(fast_exp2(ls), z1, g);
    z1 = z2; z2 = z2n; ld += ls;
}

// ---------------- main flow: whole table in LDS (R0 structure), 2 samples/thread
// 256 blocks x 1024 threads = 1 block/CU (LDS 153600 B), 16 waves/CU, zero
// barriers in the main loop. R4 proved per-layer staging+barriers lose 28 us
// to sync stalls; this regime measured 103k cyc/CU vs the 75k LDS-pipe floor.
__global__ __launch_bounds__(1024) void flow_lut(
    const float4* __restrict__ x,      // pairs of float2 samples
    const float4* __restrict__ ws,     // [NLAYER][CELLS] slope/intercept cells
    float4* __restrict__ out_z,
    float2* __restrict__ out_ld,
    int npair)
{
    __shared__ __align__(16) float4 lds[TABLE_FLOAT4];   // 153600 B
    for (int i = threadIdx.x; i < TABLE_FLOAT4; i += blockDim.x) lds[i] = ws[i];
    __syncthreads();

    const int stride = gridDim.x * blockDim.x;
    for (int p = blockIdx.x * blockDim.x + threadIdx.x; p < npair; p += stride) {
        float4 xi = x[p];
        float az1 = xi.y, az2 = xi.x, ald = 0.0f;
        float bz1 = xi.w, bz2 = xi.z, bld = 0.0f;
#pragma unroll
        for (int l = 0; l < NLAYER; ++l) {
            const float4* T = lds + l * CELLS;
            couple(T, az1, az2, ald);
            couple(T, bz1, bz2, bld);
        }
        out_z[p]  = make_float4(az1, az2, bz1, bz2);
        out_ld[p] = make_float2(ald * LN2F, bld * LN2F);
    }
}

extern "C" void kernel_launch(void* const* d_in, const int* in_sizes, int n_in,
                              void* d_out, int out_size, void* d_ws, size_t ws_size,
                              hipStream_t stream) {
    const int n = in_sizes[0] / 2;
    const int npair = n / 2;             // N = 4194304 is even

    const float4* x       = (const float4*)d_in[0];
    const float*  scale_w = (const float*)d_in[1];
    const float*  scale_b = (const float*)d_in[2];
    const float*  sW1     = (const float*)d_in[3];
    const float*  sb1     = (const float*)d_in[4];
    const float*  sW2     = (const float*)d_in[5];
    const float*  sb2     = (const float*)d_in[6];
    const float*  sW3     = (const float*)d_in[7];
    const float*  sb3     = (const float*)d_in[8];
    const float*  tW1     = (const float*)d_in[9];
    const float*  tb1     = (const float*)d_in[10];
    const float*  tW2     = (const float*)d_in[11];
    const float*  tb2     = (const float*)d_in[12];
    const float*  tW3     = (const float*)d_in[13];
    const float*  tb3     = (const float*)d_in[14];

    float4* out_z  = (float4*)d_out;
    float2* out_ld = (float2*)((float*)d_out + (size_t)2 * n);

    build_tables<<<30, 640, 0, stream>>>(scale_w, scale_b,
        sW1, sb1, sW2, sb2, sW3, sb3,
        tW1, tb1, tW2, tb2, tW3, tb3, (float*)d_ws);

    flow_lut<<<256, 1024, 0, stream>>>(x, (const float4*)d_ws, out_z, out_ld, npair);
}

// Round 6
// 146.043 us; speedup vs baseline: 3.6790x; 1.0183x over previous
//
#include <hip/hip_runtime.h>
#include <math.h>

#define SLOPE 0.01f
#define NLAYER 15
#define FINE_CELLS 512            // [-2, 2), h = 1/128
#define COARSE_CELLS 128          // [-32, 32), h = 1/2; extrapolate outside via clamped end cells
#define CELLS 640                 // per layer; cell = float4 (s_m, s_c, t_m, t_c) slope/intercept
#define FINE_NODES 513
#define NODES_PER_NET 642
#define TABLE_FLOAT4 (NLAYER * CELLS)        // 9600 float4 = 153600 B
#define INV_LN2 1.4426950408889634f
#define LN2F 0.6931471805599453f

__device__ __forceinline__ float fast_exp2(float x) {
#if __has_builtin(__builtin_amdgcn_exp2f)
    return __builtin_amdgcn_exp2f(x);
#else
    return __expf(x * LN2F);
#endif
}

// ---------------- exact scalar->32->16->1 MLP (precompute only) ----------------
__device__ __forceinline__ float mlp_exact(
    float x1,
    const float* __restrict__ W1, const float* __restrict__ b1,
    const float* __restrict__ W2, const float* __restrict__ b2,
    const float* __restrict__ W3, float b3)
{
    float h2[16];
#pragma unroll
    for (int n = 0; n < 16; ++n) h2[n] = b2[n];
#pragma unroll 2
    for (int j = 0; j < 32; ++j) {
        float h = fmaf(W1[j], x1, b1[j]);
        h = fmaxf(h, SLOPE * h);
#pragma unroll
        for (int n = 0; n < 16; ++n) h2[n] = fmaf(h, W2[j * 16 + n], h2[n]);
    }
    float o = b3;
#pragma unroll
    for (int n = 0; n < 16; ++n) {
        float h = fmaxf(h2[n], SLOPE * h2[n]);
        o = fmaf(h, W3[n], o);
    }
    return o;
}

// ---------------- build: one block per net (30 blocks) ----
// Cell c stores slope/intercept so eval is a single fma in x:
//   which==0 (s-net): (.x,.y) = (m, c) with ls2(x) = m*x + c   [log2 units]
//   which==1 (t-net): (.z,.w) = (m, c) with g(x)   = m*x + c
// (verified: same absmax 0.125 as the lerp table, R4/R5)
__global__ __launch_bounds__(640) void build_tables(
    const float* __restrict__ scale_w, const float* __restrict__ scale_b,
    const float* __restrict__ sW1, const float* __restrict__ sb1,
    const float* __restrict__ sW2, const float* __restrict__ sb2,
    const float* __restrict__ sW3, const float* __restrict__ sb3,
    const float* __restrict__ tW1, const float* __restrict__ tb1,
    const float* __restrict__ tW2, const float* __restrict__ tb2,
    const float* __restrict__ tW3, const float* __restrict__ tb3,
    float* __restrict__ ws)
{
    const int m = blockIdx.x;            // 0..29
    const int l = m >> 1;
    const int which = m & 1;             // 0 = s-net, 1 = t-net
    const float* W1 = (which ? tW1 : sW1) + l * 32;
    const float* b1 = (which ? tb1 : sb1) + l * 32;
    const float* W2 = (which ? tW2 : sW2) + l * 512;
    const float* b2 = (which ? tb2 : sb2) + l * 16;
    const float* W3 = (which ? tW3 : sW3) + l * 16;
    const float  b3 = which ? tb3[l] : sb3[l];

    __shared__ float nodes[NODES_PER_NET];

    for (int i = threadIdx.x; i < NODES_PER_NET; i += blockDim.x) {
        const float x = (i < FINE_NODES) ? (-2.0f + (float)i * (1.0f / 128.0f))
                                         : (-32.0f + (float)(i - FINE_NODES) * 0.5f);
        float o = mlp_exact(x, W1, b1, W2, b2, W3, b3);
        nodes[i] = which ? o : fmaf(tanhf(o), scale_w[l], scale_b[l]) * INV_LN2;
    }
    __syncthreads();

    for (int c = threadIdx.x; c < CELLS; c += blockDim.x) {
        int base; float x_lo, invh;
        if (c < FINE_CELLS) { base = c;     x_lo = -2.0f  + (float)c * (1.0f / 128.0f); invh = 128.0f; }
        else                { base = c + 1; x_lo = -32.0f + (float)(c - FINE_CELLS) * 0.5f; invh = 2.0f; }
        float lo = nodes[base], hi = nodes[base + 1];
        float slope = (hi - lo) * invh;
        float icpt  = fmaf(-slope, x_lo, lo);
        *(float2*)(ws + ((size_t)(l * CELLS + c) * 4) + which * 2) = make_float2(slope, icpt);
    }
}

// ---------------- cell index ----------------
// Fine: uf = 128x+256 in [0,512) -> trunc == floor (non-negative).
// Coarse: med3-clamp to [512,639] in float (1 inst), then one cvt.
__device__ __forceinline__ int cell_index(float x) {
    float uf = fmaf(x, 128.0f, 256.0f);
    float uc = fmaf(x, 2.0f, 576.0f);
    float ucl = fminf(fmaxf(uc, 512.0f), 639.0f);   // -> v_med3_f32
    float u = (fabsf(x) < 2.0f) ? uf : ucl;
    return (int)u;
}

// ---------------- main flow: whole table in LDS (R0 structure) ----------------
// 256 blocks x 1024 threads = 1 block/CU (LDS 153600 B), 16 waves/CU, zero
// barriers in the main loop. R6: 4 independent chains per thread iteration
// (2 float4 sample-pairs) -> 4 ds_read_b128 in flight per layer step instead
// of 2, to raise DS-pipe utilization (was ~60-75%; latency-bound at 2-deep).
__global__ __launch_bounds__(1024) void flow_lut(
    const float4* __restrict__ x,      // pairs of float2 samples
    const float4* __restrict__ ws,     // [NLAYER][CELLS] slope/intercept cells
    float4* __restrict__ out_z,
    float2* __restrict__ out_ld,
    int npair)
{
    __shared__ __align__(16) float4 lds[TABLE_FLOAT4];   // 153600 B
    for (int i = threadIdx.x; i < TABLE_FLOAT4; i += blockDim.x) lds[i] = ws[i];
    __syncthreads();

    const int tid = blockIdx.x * blockDim.x + threadIdx.x;
    const int stride = gridDim.x * blockDim.x;

    for (int p0 = tid; p0 < npair; p0 += 2 * stride) {
        const int p1 = p0 + stride;
        const bool has1 = (p1 < npair);
        float4 xa = x[p0];
        float4 xb = has1 ? x[p1] : make_float4(0.f, 0.f, 0.f, 0.f);

        float az1 = xa.y, az2 = xa.x, ald = 0.f;
        float bz1 = xa.w, bz2 = xa.z, bld = 0.f;
        float cz1 = xb.y, cz2 = xb.x, cld = 0.f;
        float dz1 = xb.w, dz2 = xb.z, dld = 0.f;

#pragma unroll
        for (int l = 0; l < NLAYER; ++l) {
            const float4* T = lds + l * CELLS;
            // 4 independent gathers issued before any dependent VALU
            int ia = cell_index(az2);
            int ib = cell_index(bz2);
            int ic = cell_index(cz2);
            int id = cell_index(dz2);
            float4 ca = T[ia];
            float4 cb = T[ib];
            float4 cc = T[ic];
            float4 cd = T[id];

            float als = fmaf(ca.x, az2, ca.y);
            float ag  = fmaf(ca.z, az2, ca.w);
            float bls = fmaf(cb.x, bz2, cb.y);
            float bg  = fmaf(cb.z, bz2, cb.w);
            float cls = fmaf(cc.x, cz2, cc.y);
            float cg  = fmaf(cc.z, cz2, cc.w);
            float dls = fmaf(cd.x, dz2, cd.y);
            float dg  = fmaf(cd.z, dz2, cd.w);

            float az2n = fmaf(fast_exp2(als), az1, ag);
            float bz2n = fmaf(fast_exp2(bls), bz1, bg);
            float cz2n = fmaf(fast_exp2(cls), cz1, cg);
            float dz2n = fmaf(fast_exp2(dls), dz1, dg);

            az1 = az2; az2 = az2n; ald += als;
            bz1 = bz2; bz2 = bz2n; bld += bls;
            cz1 = cz2; cz2 = cz2n; cld += cls;
            dz1 = dz2; dz2 = dz2n; dld += dls;
        }

        out_z[p0]  = make_float4(az1, az2, bz1, bz2);
        out_ld[p0] = make_float2(ald * LN2F, bld * LN2F);
        if (has1) {
            out_z[p1]  = make_float4(cz1, cz2, dz1, dz2);
            out_ld[p1] = make_float2(cld * LN2F, dld * LN2F);
        }
    }
}

extern "C" void kernel_launch(void* const* d_in, const int* in_sizes, int n_in,
                              void* d_out, int out_size, void* d_ws, size_t ws_size,
                              hipStream_t stream) {
    const int n = in_sizes[0] / 2;
    const int npair = n / 2;             // N = 4194304 is even

    const float4* x       = (const float4*)d_in[0];
    const float*  scale_w = (const float*)d_in[1];
    const float*  scale_b = (const float*)d_in[2];
    const float*  sW1     = (const float*)d_in[3];
    const float*  sb1     = (const float*)d_in[4];
    const float*  sW2     = (const float*)d_in[5];
    const float*  sb2     = (const float*)d_in[6];
    const float*  sW3     = (const float*)d_in[7];
    const float*  sb3     = (const float*)d_in[8];
    const float*  tW1     = (const float*)d_in[9];
    const float*  tb1     = (const float*)d_in[10];
    const float*  tW2     = (const float*)d_in[11];
    const float*  tb2     = (const float*)d_in[12];
    const float*  tW3     = (const float*)d_in[13];
    const float*  tb3     = (const float*)d_in[14];

    float4* out_z  = (float4*)d_out;
    float2* out_ld = (float2*)((float*)d_out + (size_t)2 * n);

    build_tables<<<30, 640, 0, stream>>>(scale_w, scale_b,
        sW1, sb1, sW2, sb2, sW3, sb3,
        tW1, tb1, tW2, tb2, tW3, tb3, (float*)d_ws);

    flow_lut<<<256, 1024, 0, stream>>>(x, (const float4*)d_ws, out_z, out_ld, npair);
}